// Round 8
// baseline (175.212 us; speedup 1.0000x reference)
//
#include <hip/hip_runtime.h>

#define B_ 16
#define N_ 16384
#define D_ 256
#define G_ 256
#define EPSF 1e-6f

#define DEV_LDF(p) __hip_atomic_load((p), __ATOMIC_RELAXED, __HIP_MEMORY_SCOPE_AGENT)

// ---- DPP wave-64 sum: row_shr 1/2/4/8 + row_bcast15/31, broadcast via readlane(63).
template <int CTRL>
__device__ __forceinline__ float dpp_add_step(float x) {
    const int y = __builtin_amdgcn_update_dpp(0, __float_as_int(x), CTRL, 0xF, 0xF, false);
    return x + __int_as_float(y);
}
__device__ __forceinline__ float wave_sum64(float x) {
    x = dpp_add_step<0x111>(x);   // row_shr:1
    x = dpp_add_step<0x112>(x);   // row_shr:2
    x = dpp_add_step<0x114>(x);   // row_shr:4
    x = dpp_add_step<0x118>(x);   // row_shr:8
    x = dpp_add_step<0x142>(x);   // row_bcast15
    x = dpp_add_step<0x143>(x);   // row_bcast31 -> lane 63 has wave total
    return __int_as_float(__builtin_amdgcn_readlane(__float_as_int(x), 63));
}

// ---- K0: per-image counting sort (16 blocks x 1024); block 0 zeroes counters ----
__global__ __launch_bounds__(1024) void k_sort(const int* __restrict__ gt,
                                               int* __restrict__ counts,
                                               int* __restrict__ starts,
                                               unsigned short* __restrict__ sorted,
                                               int* __restrict__ done) {
    __shared__ int hist[G_];
    __shared__ int scn[G_];
    const int tid = threadIdx.x, b = blockIdx.x;
    if (b == 0 && tid < 17) done[tid] = 0;      // done[0..15]=per-image, done[16]=all
    if (tid < G_) hist[tid] = 0;
    __syncthreads();
    const int base = b * N_;
    #pragma unroll
    for (int k = 0; k < N_/1024; ++k)
        atomicAdd(&hist[gt[base + k*1024 + tid]], 1);
    __syncthreads();
    int c = 0;
    if (tid < G_) {
        c = hist[tid];
        counts[b*G_ + tid] = c;
        scn[tid] = c;
    }
    __syncthreads();
    for (int off = 1; off < G_; off <<= 1) {
        int v = 0;
        if (tid < G_ && tid >= off) v = scn[tid - off];
        __syncthreads();
        if (tid < G_) scn[tid] += v;
        __syncthreads();
    }
    if (tid < G_) {
        const int st = scn[tid] - c;            // exclusive prefix
        starts[b*G_ + tid] = st;
        hist[tid] = st;                          // reuse as cursor
    }
    __syncthreads();
    #pragma unroll
    for (int k = 0; k < N_/1024; ++k) {
        const int r = k*1024 + tid;
        const int g = gt[base + r];
        const int pos = atomicAdd(&hist[g], 1);
        sorted[base + pos] = (unsigned short)r;
    }
}

// ---- K1: one WAVE per (b,g) group; last block per image runs tags inline;
//          last image-finisher writes out[0]. 2-kernel graph total. ----
__global__ __launch_bounds__(256, 5) void k_fused(const float* __restrict__ pred,
                                                  const unsigned short* __restrict__ sorted,
                                                  const int* __restrict__ starts,
                                                  const int* __restrict__ counts,
                                                  float* __restrict__ sums,
                                                  float* __restrict__ pull_g,
                                                  int* __restrict__ done,
                                                  float* __restrict__ lossv,
                                                  float* __restrict__ out) {
    const int tid = threadIdx.x, lane = tid & 63, w = tid >> 6;
    const int gi = (blockIdx.x << 2) | w;          // = b*G_ + g
    const int b = gi >> 8;                          // = blockIdx.x >> 6
    const int start = starts[gi], cnt = counts[gi];
    const int c = lane * 4;

    if (cnt == 0) {
        float4 z = make_float4(0.f,0.f,0.f,0.f);
        *(float4*)&sums[(size_t)gi*D_ + c] = z;
        if (lane == 0) pull_g[gi] = 0.f;
    } else {
        const float* predb = pred + (size_t)b*N_*D_;
        const unsigned short* sortb = sorted + b*N_ + start;

        float4 acc  = make_float4(0.f,0.f,0.f,0.f);    // S (this lane's 4 dims)
        float4 uacc = make_float4(0.f,0.f,0.f,0.f);    // U
        int i = 0;

        if (cnt <= 128) {
            const int ids0 = (int)sortb[min(lane, cnt-1)];
            int ids1 = 0;
            if (cnt > 64) ids1 = (int)sortb[min(64 + lane, cnt-1)];
            #define GET2(k) (((k) < 64) ? __builtin_amdgcn_readlane(ids0, (k)) \
                                        : __builtin_amdgcn_readlane(ids1, (k) - 64))
            for (; i + 8 <= cnt; i += 8) {
                const int r0 = GET2(i+0), r1 = GET2(i+1), r2 = GET2(i+2), r3 = GET2(i+3);
                const int r4 = GET2(i+4), r5 = GET2(i+5), r6 = GET2(i+6), r7 = GET2(i+7);
                const float4 p0 = *(const float4*)&predb[(size_t)r0*D_ + c];
                const float4 p1 = *(const float4*)&predb[(size_t)r1*D_ + c];
                const float4 p2 = *(const float4*)&predb[(size_t)r2*D_ + c];
                const float4 p3 = *(const float4*)&predb[(size_t)r3*D_ + c];
                const float4 p4 = *(const float4*)&predb[(size_t)r4*D_ + c];
                const float4 p5 = *(const float4*)&predb[(size_t)r5*D_ + c];
                const float4 p6 = *(const float4*)&predb[(size_t)r6*D_ + c];
                const float4 p7 = *(const float4*)&predb[(size_t)r7*D_ + c];
                float n0 = p0.x*p0.x + p0.y*p0.y + p0.z*p0.z + p0.w*p0.w;
                float n1 = p1.x*p1.x + p1.y*p1.y + p1.z*p1.z + p1.w*p1.w;
                float n2 = p2.x*p2.x + p2.y*p2.y + p2.z*p2.z + p2.w*p2.w;
                float n3 = p3.x*p3.x + p3.y*p3.y + p3.z*p3.z + p3.w*p3.w;
                float n4 = p4.x*p4.x + p4.y*p4.y + p4.z*p4.z + p4.w*p4.w;
                float n5 = p5.x*p5.x + p5.y*p5.y + p5.z*p5.z + p5.w*p5.w;
                float n6 = p6.x*p6.x + p6.y*p6.y + p6.z*p6.z + p6.w*p6.w;
                float n7 = p7.x*p7.x + p7.y*p7.y + p7.z*p7.z + p7.w*p7.w;
                n0 = wave_sum64(n0); n1 = wave_sum64(n1);
                n2 = wave_sum64(n2); n3 = wave_sum64(n3);
                n4 = wave_sum64(n4); n5 = wave_sum64(n5);
                n6 = wave_sum64(n6); n7 = wave_sum64(n7);
                const float q0 = __frsqrt_rn(n0), q1 = __frsqrt_rn(n1);
                const float q2 = __frsqrt_rn(n2), q3 = __frsqrt_rn(n3);
                const float q4 = __frsqrt_rn(n4), q5 = __frsqrt_rn(n5);
                const float q6 = __frsqrt_rn(n6), q7 = __frsqrt_rn(n7);
                acc.x  += ((p0.x + p1.x) + (p2.x + p3.x)) + ((p4.x + p5.x) + (p6.x + p7.x));
                acc.y  += ((p0.y + p1.y) + (p2.y + p3.y)) + ((p4.y + p5.y) + (p6.y + p7.y));
                acc.z  += ((p0.z + p1.z) + (p2.z + p3.z)) + ((p4.z + p5.z) + (p6.z + p7.z));
                acc.w  += ((p0.w + p1.w) + (p2.w + p3.w)) + ((p4.w + p5.w) + (p6.w + p7.w));
                uacc.x += ((p0.x*q0 + p1.x*q1) + (p2.x*q2 + p3.x*q3)) + ((p4.x*q4 + p5.x*q5) + (p6.x*q6 + p7.x*q7));
                uacc.y += ((p0.y*q0 + p1.y*q1) + (p2.y*q2 + p3.y*q3)) + ((p4.y*q4 + p5.y*q5) + (p6.y*q6 + p7.y*q7));
                uacc.z += ((p0.z*q0 + p1.z*q1) + (p2.z*q2 + p3.z*q3)) + ((p4.z*q4 + p5.z*q5) + (p6.z*q6 + p7.z*q7));
                uacc.w += ((p0.w*q0 + p1.w*q1) + (p2.w*q2 + p3.w*q3)) + ((p4.w*q4 + p5.w*q5) + (p6.w*q6 + p7.w*q7));
            }
            for (; i < cnt; ++i) {
                const int r0 = GET2(i);
                const float4 p0 = *(const float4*)&predb[(size_t)r0*D_ + c];
                const float n0 = wave_sum64(p0.x*p0.x + p0.y*p0.y + p0.z*p0.z + p0.w*p0.w);
                const float q0 = __frsqrt_rn(n0);
                acc.x  += p0.x;    acc.y  += p0.y;    acc.z  += p0.z;    acc.w  += p0.w;
                uacc.x += p0.x*q0; uacc.y += p0.y*q0; uacc.z += p0.z*q0; uacc.w += p0.w*q0;
            }
            #undef GET2
        } else {
            for (; i < cnt; ++i) {
                const int r0 = (int)sortb[i];
                const float4 p0 = *(const float4*)&predb[(size_t)r0*D_ + c];
                const float n0 = wave_sum64(p0.x*p0.x + p0.y*p0.y + p0.z*p0.z + p0.w*p0.w);
                const float q0 = __frsqrt_rn(n0);
                acc.x  += p0.x;    acc.y  += p0.y;    acc.z  += p0.z;    acc.w  += p0.w;
                uacc.x += p0.x*q0; uacc.y += p0.y*q0; uacc.z += p0.z*q0; uacc.w += p0.w*q0;
            }
        }

        *(float4*)&sums[(size_t)gi*D_ + c] = acc;
        const float ssq = wave_sum64(acc.x*acc.x + acc.y*acc.y + acc.z*acc.z + acc.w*acc.w);
        const float dus = wave_sum64(uacc.x*acc.x + uacc.y*acc.y + uacc.z*acc.z + uacc.w*acc.w);
        if (lane == 0) pull_g[gi] = (float)cnt - dus / sqrtf(ssq);
    }

    // ---- completion: 64th block of image b runs the per-image tags phase ----
    __shared__ int islast;
    __syncthreads();
    if (tid == 0) {
        __threadfence();   // release our sums/pull_g writes at agent scope
        const int old = __hip_atomic_fetch_add(&done[b], 1, __ATOMIC_ACQ_REL,
                                               __HIP_MEMORY_SCOPE_AGENT);
        islast = (old == 63);
    }
    __syncthreads();
    if (!islast) return;

    // ---- tags phase (push via |sum of unit tags|^2 + pull combine) ----
    __shared__ float s_acc[D_];
    __shared__ float redA[256];
    __shared__ float redB[256];
    for (int i2 = tid; i2 < D_; i2 += 256) s_acc[i2] = 0.f;
    __syncthreads();

    float4 sl = make_float4(0.f, 0.f, 0.f, 0.f);
    for (int g = w; g < G_; g += 4) {
        const int cg = counts[b*G_ + g];
        const float inv = 1.0f / fmaxf((float)cg, 1.0f);
        const float* smp = &sums[((size_t)(b*G_ + g))*D_ + c];
        const float tx = DEV_LDF(smp+0)*inv, ty = DEV_LDF(smp+1)*inv;
        const float tz = DEV_LDF(smp+2)*inv, tw = DEV_LDF(smp+3)*inv;
        const float sq = wave_sum64(tx*tx + ty*ty + tz*tz + tw*tw);
        if (cg > 0) {
            const float it = __frsqrt_rn(sq);
            sl.x += tx*it; sl.y += ty*it; sl.z += tz*it; sl.w += tw*it;
        }
    }
    atomicAdd(&s_acc[c+0], sl.x);
    atomicAdd(&s_acc[c+1], sl.y);
    atomicAdd(&s_acc[c+2], sl.z);
    atomicAdd(&s_acc[c+3], sl.w);
    __syncthreads();

    const int cnt_t = counts[b*G_ + tid];
    const float v = s_acc[tid];
    redA[tid] = v * v;
    redB[tid] = (cnt_t > 0) ? 1.f : 0.f;
    __syncthreads();
    for (int s = 128; s > 0; s >>= 1) {
        if (tid < s) { redA[tid] += redA[tid + s]; redB[tid] += redB[tid + s]; }
        __syncthreads();
    }
    float ssq2 = 0.f, obj = 0.f;
    if (tid == 0) { ssq2 = redA[0]; obj = redB[0]; }
    __syncthreads();

    redA[tid] = (cnt_t > 0) ? DEV_LDF(&pull_g[b*G_ + tid]) / (float)cnt_t : 0.f;
    __syncthreads();
    for (int s = 128; s > 0; s >>= 1) {
        if (tid < s) redA[tid] += redA[tid + s];
        __syncthreads();
    }
    if (tid == 0) {
        const float push = (obj*obj - 2.f*obj + ssq2) / (((obj - 1.f)*obj + EPSF) * 2.f);
        const float pull = redA[0] / (obj + EPSF);
        const float loss = (obj > 1.f) ? (push + pull) : 0.f;
        __hip_atomic_store(&lossv[b], loss, __ATOMIC_RELEASE, __HIP_MEMORY_SCOPE_AGENT);
        const int o2 = __hip_atomic_fetch_add(&done[16], 1, __ATOMIC_ACQ_REL,
                                              __HIP_MEMORY_SCOPE_AGENT);
        if (o2 == 15) {   // all 16 images done -> final mean
            float t = 0.f;
            #pragma unroll
            for (int bb = 0; bb < B_; ++bb)
                t += __hip_atomic_load(&lossv[bb], __ATOMIC_RELAXED, __HIP_MEMORY_SCOPE_AGENT);
            out[0] = t * (1.0f / (float)B_);
        }
    }
}

extern "C" void kernel_launch(void* const* d_in, const int* in_sizes, int n_in,
                              void* d_out, int out_size, void* d_ws, size_t ws_size,
                              hipStream_t stream) {
    const float* pred = (const float*)d_in[0];
    const int*   gt   = (const int*)d_in[1];
    float* out = (float*)d_out;

    char* ws = (char*)d_ws;
    const size_t SZ_SUMS = (size_t)B_*G_*D_*sizeof(float);   // 4 MiB
    const size_t SZ_I    = (size_t)B_*G_*sizeof(int);        // 16 KiB each

    float* sums    = (float*)ws;                               ws += SZ_SUMS;
    int*   counts  = (int*)ws;                                 ws += SZ_I;
    int*   starts  = (int*)ws;                                 ws += SZ_I;
    float* pull_g  = (float*)ws;                               ws += SZ_I;
    float* lossv   = (float*)ws;                               ws += 64*sizeof(float);
    int*   done    = (int*)ws;                                 ws += 64*sizeof(int);
    unsigned short* sorted = (unsigned short*)ws;              // B*N u16 = 512 KiB

    k_sort  <<<B_,      1024, 0, stream>>>(gt, counts, starts, sorted, done);
    k_fused <<<B_*G_/4,  256, 0, stream>>>(pred, sorted, starts, counts, sums,
                                           pull_g, done, lossv, out);
}

// Round 9
// 91.015 us; speedup vs baseline: 1.9251x; 1.9251x over previous
//
#include <hip/hip_runtime.h>

#define B_ 16
#define N_ 16384
#define D_ 256
#define G_ 256
#define EPSF 1e-6f

#define DEV_LDF(p) __hip_atomic_load((p), __ATOMIC_RELAXED, __HIP_MEMORY_SCOPE_AGENT)

// ---- DPP wave-64 sum: row_shr 1/2/4/8 + row_bcast15/31, broadcast via readlane(63).
template <int CTRL>
__device__ __forceinline__ float dpp_add_step(float x) {
    const int y = __builtin_amdgcn_update_dpp(0, __float_as_int(x), CTRL, 0xF, 0xF, false);
    return x + __int_as_float(y);
}
__device__ __forceinline__ float wave_sum64(float x) {
    x = dpp_add_step<0x111>(x);   // row_shr:1
    x = dpp_add_step<0x112>(x);   // row_shr:2
    x = dpp_add_step<0x114>(x);   // row_shr:4
    x = dpp_add_step<0x118>(x);   // row_shr:8
    x = dpp_add_step<0x142>(x);   // row_bcast15
    x = dpp_add_step<0x143>(x);   // row_bcast31 -> lane 63 has wave total
    return __int_as_float(__builtin_amdgcn_readlane(__float_as_int(x), 63));
}

// ---- K0: per-image counting sort (16 blocks x 1024), int4-vectorized ----
__global__ __launch_bounds__(1024) void k_sort(const int* __restrict__ gt,
                                               int* __restrict__ counts,
                                               int* __restrict__ starts,
                                               int* __restrict__ sorted,
                                               int* __restrict__ done) {
    __shared__ int hist[G_];
    __shared__ int scn[G_];
    const int tid = threadIdx.x, b = blockIdx.x;
    if (b == 0 && tid == 0) done[0] = 0;
    if (tid < G_) hist[tid] = 0;
    __syncthreads();
    const int base = b * N_;
    #pragma unroll
    for (int k = 0; k < N_/4096; ++k) {
        const int4 g4 = *(const int4*)&gt[base + k*4096 + tid*4];
        atomicAdd(&hist[g4.x], 1);
        atomicAdd(&hist[g4.y], 1);
        atomicAdd(&hist[g4.z], 1);
        atomicAdd(&hist[g4.w], 1);
    }
    __syncthreads();
    int c = 0;
    if (tid < G_) {
        c = hist[tid];
        counts[b*G_ + tid] = c;
        scn[tid] = c;
    }
    __syncthreads();
    for (int off = 1; off < G_; off <<= 1) {
        int v = 0;
        if (tid < G_ && tid >= off) v = scn[tid - off];
        __syncthreads();
        if (tid < G_) scn[tid] += v;
        __syncthreads();
    }
    if (tid < G_) {
        const int st = scn[tid] - c;            // exclusive prefix
        starts[b*G_ + tid] = st;
        hist[tid] = st;                          // reuse as cursor
    }
    __syncthreads();
    #pragma unroll
    for (int k = 0; k < N_/4096; ++k) {
        const int r = k*4096 + tid*4;
        const int4 g4 = *(const int4*)&gt[base + r];
        sorted[base + atomicAdd(&hist[g4.x], 1)] = r;
        sorted[base + atomicAdd(&hist[g4.y], 1)] = r + 1;
        sorted[base + atomicAdd(&hist[g4.z], 1)] = r + 2;
        sorted[base + atomicAdd(&hist[g4.w], 1)] = r + 3;
    }
}

// ---- K1: one WAVE per (b,g) group. No LDS, no barriers, no atomics. ----
// (round-7 verbatim: keep this kernel SMALL so regalloc keeps 8 loads in flight)
__global__ __launch_bounds__(256, 5) void k_fused(const float* __restrict__ pred,
                                                  const int* __restrict__ sorted,
                                                  const int* __restrict__ starts,
                                                  const int* __restrict__ counts,
                                                  float* __restrict__ sums,
                                                  float* __restrict__ pull_g) {
    const int tid = threadIdx.x, lane = tid & 63, w = tid >> 6;
    const int gi = (blockIdx.x << 2) | w;          // = b*G_ + g
    const int b = gi >> 8;
    const int start = starts[gi], cnt = counts[gi];
    const int c = lane * 4;

    if (cnt == 0) {
        float4 z = make_float4(0.f,0.f,0.f,0.f);
        *(float4*)&sums[(size_t)gi*D_ + c] = z;
        if (lane == 0) pull_g[gi] = 0.f;
        return;                                    // wave-level return: no barriers in kernel
    }

    const float* predb = pred + (size_t)b*N_*D_;
    const int*   sortb = sorted + b*N_ + start;

    float4 acc  = make_float4(0.f,0.f,0.f,0.f);    // S (this lane's 4 dims)
    float4 uacc = make_float4(0.f,0.f,0.f,0.f);    // U
    int i = 0;

    if (cnt <= 128) {
        const int ids0 = sortb[min(lane, cnt-1)];
        int ids1 = 0;
        if (cnt > 64) ids1 = sortb[min(64 + lane, cnt-1)];
        #define GET2(k) (((k) < 64) ? __builtin_amdgcn_readlane(ids0, (k)) \
                                    : __builtin_amdgcn_readlane(ids1, (k) - 64))
        for (; i + 8 <= cnt; i += 8) {
            const int r0 = GET2(i+0), r1 = GET2(i+1), r2 = GET2(i+2), r3 = GET2(i+3);
            const int r4 = GET2(i+4), r5 = GET2(i+5), r6 = GET2(i+6), r7 = GET2(i+7);
            const float4 p0 = *(const float4*)&predb[(size_t)r0*D_ + c];
            const float4 p1 = *(const float4*)&predb[(size_t)r1*D_ + c];
            const float4 p2 = *(const float4*)&predb[(size_t)r2*D_ + c];
            const float4 p3 = *(const float4*)&predb[(size_t)r3*D_ + c];
            const float4 p4 = *(const float4*)&predb[(size_t)r4*D_ + c];
            const float4 p5 = *(const float4*)&predb[(size_t)r5*D_ + c];
            const float4 p6 = *(const float4*)&predb[(size_t)r6*D_ + c];
            const float4 p7 = *(const float4*)&predb[(size_t)r7*D_ + c];
            float n0 = p0.x*p0.x + p0.y*p0.y + p0.z*p0.z + p0.w*p0.w;
            float n1 = p1.x*p1.x + p1.y*p1.y + p1.z*p1.z + p1.w*p1.w;
            float n2 = p2.x*p2.x + p2.y*p2.y + p2.z*p2.z + p2.w*p2.w;
            float n3 = p3.x*p3.x + p3.y*p3.y + p3.z*p3.z + p3.w*p3.w;
            float n4 = p4.x*p4.x + p4.y*p4.y + p4.z*p4.z + p4.w*p4.w;
            float n5 = p5.x*p5.x + p5.y*p5.y + p5.z*p5.z + p5.w*p5.w;
            float n6 = p6.x*p6.x + p6.y*p6.y + p6.z*p6.z + p6.w*p6.w;
            float n7 = p7.x*p7.x + p7.y*p7.y + p7.z*p7.z + p7.w*p7.w;
            n0 = wave_sum64(n0); n1 = wave_sum64(n1);
            n2 = wave_sum64(n2); n3 = wave_sum64(n3);
            n4 = wave_sum64(n4); n5 = wave_sum64(n5);
            n6 = wave_sum64(n6); n7 = wave_sum64(n7);
            const float q0 = __frsqrt_rn(n0), q1 = __frsqrt_rn(n1);
            const float q2 = __frsqrt_rn(n2), q3 = __frsqrt_rn(n3);
            const float q4 = __frsqrt_rn(n4), q5 = __frsqrt_rn(n5);
            const float q6 = __frsqrt_rn(n6), q7 = __frsqrt_rn(n7);
            acc.x  += ((p0.x + p1.x) + (p2.x + p3.x)) + ((p4.x + p5.x) + (p6.x + p7.x));
            acc.y  += ((p0.y + p1.y) + (p2.y + p3.y)) + ((p4.y + p5.y) + (p6.y + p7.y));
            acc.z  += ((p0.z + p1.z) + (p2.z + p3.z)) + ((p4.z + p5.z) + (p6.z + p7.z));
            acc.w  += ((p0.w + p1.w) + (p2.w + p3.w)) + ((p4.w + p5.w) + (p6.w + p7.w));
            uacc.x += ((p0.x*q0 + p1.x*q1) + (p2.x*q2 + p3.x*q3)) + ((p4.x*q4 + p5.x*q5) + (p6.x*q6 + p7.x*q7));
            uacc.y += ((p0.y*q0 + p1.y*q1) + (p2.y*q2 + p3.y*q3)) + ((p4.y*q4 + p5.y*q5) + (p6.y*q6 + p7.y*q7));
            uacc.z += ((p0.z*q0 + p1.z*q1) + (p2.z*q2 + p3.z*q3)) + ((p4.z*q4 + p5.z*q5) + (p6.z*q6 + p7.z*q7));
            uacc.w += ((p0.w*q0 + p1.w*q1) + (p2.w*q2 + p3.w*q3)) + ((p4.w*q4 + p5.w*q5) + (p6.w*q6 + p7.w*q7));
        }
        for (; i < cnt; ++i) {
            const int r0 = GET2(i);
            const float4 p0 = *(const float4*)&predb[(size_t)r0*D_ + c];
            const float n0 = wave_sum64(p0.x*p0.x + p0.y*p0.y + p0.z*p0.z + p0.w*p0.w);
            const float q0 = __frsqrt_rn(n0);
            acc.x  += p0.x;    acc.y  += p0.y;    acc.z  += p0.z;    acc.w  += p0.w;
            uacc.x += p0.x*q0; uacc.y += p0.y*q0; uacc.z += p0.z*q0; uacc.w += p0.w*q0;
        }
        #undef GET2
    } else {
        for (; i < cnt; ++i) {
            const int r0 = sortb[i];
            const float4 p0 = *(const float4*)&predb[(size_t)r0*D_ + c];
            const float n0 = wave_sum64(p0.x*p0.x + p0.y*p0.y + p0.z*p0.z + p0.w*p0.w);
            const float q0 = __frsqrt_rn(n0);
            acc.x  += p0.x;    acc.y  += p0.y;    acc.z  += p0.z;    acc.w  += p0.w;
            uacc.x += p0.x*q0; uacc.y += p0.y*q0; uacc.z += p0.z*q0; uacc.w += p0.w*q0;
        }
    }

    *(float4*)&sums[(size_t)gi*D_ + c] = acc;
    const float ssq = wave_sum64(acc.x*acc.x + acc.y*acc.y + acc.z*acc.z + acc.w*acc.w);
    const float dus = wave_sum64(uacc.x*acc.x + uacc.y*acc.y + uacc.z*acc.z + uacc.w*acc.w);
    if (lane == 0) pull_g[gi] = (float)cnt - dus / sqrtf(ssq);
}

// ---- K2: per-image push + pull combine; last image-finisher writes out[0] ----
__global__ __launch_bounds__(256) void k_tags(const float* __restrict__ sums,
                                              const int* __restrict__ counts,
                                              const float* __restrict__ pull_g,
                                              float* __restrict__ lossv,
                                              int* __restrict__ done,
                                              float* __restrict__ out) {
    const int b = blockIdx.x;
    const int tid = threadIdx.x;
    const int lane = tid & 63;
    const int wave = tid >> 6;
    __shared__ float s_acc[D_];
    __shared__ float redA[256];
    __shared__ float redB[256];

    for (int i = tid; i < D_; i += 256) s_acc[i] = 0.f;
    __syncthreads();

    const int c = lane * 4;
    float4 sl = make_float4(0.f, 0.f, 0.f, 0.f);
    for (int g = wave; g < G_; g += 4) {
        const int cnt = counts[b*G_ + g];
        const float inv = 1.0f / fmaxf((float)cnt, 1.0f);
        const float4 sm = *(const float4*)&sums[((size_t)(b*G_ + g))*D_ + c];
        const float tx = sm.x*inv, tyv = sm.y*inv, tz = sm.z*inv, tw = sm.w*inv;
        const float sq = wave_sum64(tx*tx + tyv*tyv + tz*tz + tw*tw);
        if (cnt > 0) {
            const float it = __frsqrt_rn(sq);
            sl.x += tx*it; sl.y += tyv*it; sl.z += tz*it; sl.w += tw*it;
        }
    }
    atomicAdd(&s_acc[c+0], sl.x);
    atomicAdd(&s_acc[c+1], sl.y);
    atomicAdd(&s_acc[c+2], sl.z);
    atomicAdd(&s_acc[c+3], sl.w);
    __syncthreads();

    const int cnt_t = counts[b*G_ + tid];
    const float v = s_acc[tid];
    redA[tid] = v * v;
    redB[tid] = (cnt_t > 0) ? 1.f : 0.f;
    __syncthreads();
    for (int s = 128; s > 0; s >>= 1) {
        if (tid < s) { redA[tid] += redA[tid + s]; redB[tid] += redB[tid + s]; }
        __syncthreads();
    }
    float ssq = 0.f, obj = 0.f;
    if (tid == 0) { ssq = redA[0]; obj = redB[0]; }
    __syncthreads();

    redA[tid] = (cnt_t > 0) ? pull_g[b*G_ + tid] / (float)cnt_t : 0.f;
    __syncthreads();
    for (int s = 128; s > 0; s >>= 1) {
        if (tid < s) redA[tid] += redA[tid + s];
        __syncthreads();
    }
    if (tid == 0) {
        const float push = (obj*obj - 2.f*obj + ssq) / (((obj - 1.f)*obj + EPSF) * 2.f);
        const float pull = redA[0] / (obj + EPSF);
        const float loss = (obj > 1.f) ? (push + pull) : 0.f;
        __hip_atomic_store(&lossv[b], loss, __ATOMIC_RELEASE, __HIP_MEMORY_SCOPE_AGENT);
        const int o = __hip_atomic_fetch_add(&done[0], 1, __ATOMIC_ACQ_REL,
                                             __HIP_MEMORY_SCOPE_AGENT);
        if (o == B_ - 1) {    // last image: final mean
            float t = 0.f;
            #pragma unroll
            for (int bb = 0; bb < B_; ++bb)
                t += __hip_atomic_load(&lossv[bb], __ATOMIC_RELAXED, __HIP_MEMORY_SCOPE_AGENT);
            out[0] = t * (1.0f / (float)B_);
        }
    }
}

extern "C" void kernel_launch(void* const* d_in, const int* in_sizes, int n_in,
                              void* d_out, int out_size, void* d_ws, size_t ws_size,
                              hipStream_t stream) {
    const float* pred = (const float*)d_in[0];
    const int*   gt   = (const int*)d_in[1];
    float* out = (float*)d_out;

    char* ws = (char*)d_ws;
    const size_t SZ_SUMS = (size_t)B_*G_*D_*sizeof(float);   // 4 MiB
    const size_t SZ_I    = (size_t)B_*G_*sizeof(int);        // 16 KiB each

    float* sums    = (float*)ws;                               ws += SZ_SUMS;
    int*   counts  = (int*)ws;                                 ws += SZ_I;
    int*   starts  = (int*)ws;                                 ws += SZ_I;
    float* pull_g  = (float*)ws;                               ws += SZ_I;
    float* lossv   = (float*)ws;                               ws += 64*sizeof(float);
    int*   done    = (int*)ws;                                 ws += 64*sizeof(int);
    int*   sorted  = (int*)ws;                                 // B*N ints = 1 MiB

    k_sort  <<<B_,      1024, 0, stream>>>(gt, counts, starts, sorted, done);
    k_fused <<<B_*G_/4,  256, 0, stream>>>(pred, sorted, starts, counts, sums, pull_g);
    k_tags  <<<B_,       256, 0, stream>>>(sums, counts, pull_g, lossv, done, out);
}

// Round 10
// 90.738 us; speedup vs baseline: 1.9310x; 1.0030x over previous
//
#include <hip/hip_runtime.h>

#define B_ 16
#define N_ 16384
#define D_ 256
#define G_ 256
#define EPSF 1e-6f

// ---- DPP wave-64 sum: row_shr 1/2/4/8 + row_bcast15/31, broadcast via readlane(63).
template <int CTRL>
__device__ __forceinline__ float dpp_add_step(float x) {
    const int y = __builtin_amdgcn_update_dpp(0, __float_as_int(x), CTRL, 0xF, 0xF, false);
    return x + __int_as_float(y);
}
__device__ __forceinline__ float wave_sum64(float x) {
    x = dpp_add_step<0x111>(x);   // row_shr:1
    x = dpp_add_step<0x112>(x);   // row_shr:2
    x = dpp_add_step<0x114>(x);   // row_shr:4
    x = dpp_add_step<0x118>(x);   // row_shr:8
    x = dpp_add_step<0x142>(x);   // row_bcast15
    x = dpp_add_step<0x143>(x);   // row_bcast31 -> lane 63 has wave total
    return __int_as_float(__builtin_amdgcn_readlane(__float_as_int(x), 63));
}

// ---- K0: per-image counting sort (16 blocks x 1024), int4-vectorized ----
__global__ __launch_bounds__(1024) void k_sort(const int* __restrict__ gt,
                                               int* __restrict__ counts,
                                               int* __restrict__ starts,
                                               int* __restrict__ sorted,
                                               int* __restrict__ done) {
    __shared__ int hist[G_];
    __shared__ int scn[G_];
    const int tid = threadIdx.x, b = blockIdx.x;
    if (b == 0 && tid == 0) done[0] = 0;
    if (tid < G_) hist[tid] = 0;
    __syncthreads();
    const int base = b * N_;
    #pragma unroll
    for (int k = 0; k < N_/4096; ++k) {
        const int4 g4 = *(const int4*)&gt[base + k*4096 + tid*4];
        atomicAdd(&hist[g4.x], 1);
        atomicAdd(&hist[g4.y], 1);
        atomicAdd(&hist[g4.z], 1);
        atomicAdd(&hist[g4.w], 1);
    }
    __syncthreads();
    int c = 0;
    if (tid < G_) {
        c = hist[tid];
        counts[b*G_ + tid] = c;
        scn[tid] = c;
    }
    __syncthreads();
    for (int off = 1; off < G_; off <<= 1) {
        int v = 0;
        if (tid < G_ && tid >= off) v = scn[tid - off];
        __syncthreads();
        if (tid < G_) scn[tid] += v;
        __syncthreads();
    }
    if (tid < G_) {
        const int st = scn[tid] - c;            // exclusive prefix
        starts[b*G_ + tid] = st;
        hist[tid] = st;                          // reuse as cursor
    }
    __syncthreads();
    #pragma unroll
    for (int k = 0; k < N_/4096; ++k) {
        const int r = k*4096 + tid*4;
        const int4 g4 = *(const int4*)&gt[base + r];
        sorted[base + atomicAdd(&hist[g4.x], 1)] = r;
        sorted[base + atomicAdd(&hist[g4.y], 1)] = r + 1;
        sorted[base + atomicAdd(&hist[g4.z], 1)] = r + 2;
        sorted[base + atomicAdd(&hist[g4.w], 1)] = r + 3;
    }
}

// ---- K1: TWO waves per (b,g) group (each sums a contiguous half), tiny LDS
//      combine. Hot loop identical to round-7 (8 float4 loads in flight, DPP
//      norms). Epilogue deliberately minimal (round-8 lesson: heavy epilogues
//      poison regalloc and serialize the load pipeline). ----
__global__ __launch_bounds__(256, 5) void k_fused(const float* __restrict__ pred,
                                                  const int* __restrict__ sorted,
                                                  const int* __restrict__ starts,
                                                  const int* __restrict__ counts,
                                                  float* __restrict__ sums,
                                                  float* __restrict__ pull_g) {
    __shared__ float comb[2][2][2][D_];   // [sub][half][S|U][dim] = 8 KiB
    const int tid = threadIdx.x, lane = tid & 63, w = tid >> 6;
    const int sub = w >> 1, h = w & 1;
    const int gi = (blockIdx.x << 1) | sub;        // = b*G_ + g
    const int b = gi >> 8;
    const int start = starts[gi], cnt = counts[gi];
    const int c = lane * 4;

    const float* predb = pred + (size_t)b*N_*D_;
    const int*   sortb = sorted + b*N_ + start;

    float4 acc  = make_float4(0.f,0.f,0.f,0.f);    // S partial (this lane's 4 dims)
    float4 uacc = make_float4(0.f,0.f,0.f,0.f);    // U partial

    const int half = (cnt + 1) >> 1;
    const int lo = h * half;
    const int hi = min(cnt, lo + half);
    int i = lo;

    if (cnt > 0 && cnt <= 128) {
        const int ids0 = sortb[min(lane, cnt-1)];
        int ids1 = 0;
        if (cnt > 64) ids1 = sortb[min(64 + lane, cnt-1)];
        #define GET2(k) (((k) < 64) ? __builtin_amdgcn_readlane(ids0, (k)) \
                                    : __builtin_amdgcn_readlane(ids1, (k) - 64))
        for (; i + 8 <= hi; i += 8) {
            const int r0 = GET2(i+0), r1 = GET2(i+1), r2 = GET2(i+2), r3 = GET2(i+3);
            const int r4 = GET2(i+4), r5 = GET2(i+5), r6 = GET2(i+6), r7 = GET2(i+7);
            const float4 p0 = *(const float4*)&predb[(size_t)r0*D_ + c];
            const float4 p1 = *(const float4*)&predb[(size_t)r1*D_ + c];
            const float4 p2 = *(const float4*)&predb[(size_t)r2*D_ + c];
            const float4 p3 = *(const float4*)&predb[(size_t)r3*D_ + c];
            const float4 p4 = *(const float4*)&predb[(size_t)r4*D_ + c];
            const float4 p5 = *(const float4*)&predb[(size_t)r5*D_ + c];
            const float4 p6 = *(const float4*)&predb[(size_t)r6*D_ + c];
            const float4 p7 = *(const float4*)&predb[(size_t)r7*D_ + c];
            float n0 = p0.x*p0.x + p0.y*p0.y + p0.z*p0.z + p0.w*p0.w;
            float n1 = p1.x*p1.x + p1.y*p1.y + p1.z*p1.z + p1.w*p1.w;
            float n2 = p2.x*p2.x + p2.y*p2.y + p2.z*p2.z + p2.w*p2.w;
            float n3 = p3.x*p3.x + p3.y*p3.y + p3.z*p3.z + p3.w*p3.w;
            float n4 = p4.x*p4.x + p4.y*p4.y + p4.z*p4.z + p4.w*p4.w;
            float n5 = p5.x*p5.x + p5.y*p5.y + p5.z*p5.z + p5.w*p5.w;
            float n6 = p6.x*p6.x + p6.y*p6.y + p6.z*p6.z + p6.w*p6.w;
            float n7 = p7.x*p7.x + p7.y*p7.y + p7.z*p7.z + p7.w*p7.w;
            n0 = wave_sum64(n0); n1 = wave_sum64(n1);
            n2 = wave_sum64(n2); n3 = wave_sum64(n3);
            n4 = wave_sum64(n4); n5 = wave_sum64(n5);
            n6 = wave_sum64(n6); n7 = wave_sum64(n7);
            const float q0 = __frsqrt_rn(n0), q1 = __frsqrt_rn(n1);
            const float q2 = __frsqrt_rn(n2), q3 = __frsqrt_rn(n3);
            const float q4 = __frsqrt_rn(n4), q5 = __frsqrt_rn(n5);
            const float q6 = __frsqrt_rn(n6), q7 = __frsqrt_rn(n7);
            acc.x  += ((p0.x + p1.x) + (p2.x + p3.x)) + ((p4.x + p5.x) + (p6.x + p7.x));
            acc.y  += ((p0.y + p1.y) + (p2.y + p3.y)) + ((p4.y + p5.y) + (p6.y + p7.y));
            acc.z  += ((p0.z + p1.z) + (p2.z + p3.z)) + ((p4.z + p5.z) + (p6.z + p7.z));
            acc.w  += ((p0.w + p1.w) + (p2.w + p3.w)) + ((p4.w + p5.w) + (p6.w + p7.w));
            uacc.x += ((p0.x*q0 + p1.x*q1) + (p2.x*q2 + p3.x*q3)) + ((p4.x*q4 + p5.x*q5) + (p6.x*q6 + p7.x*q7));
            uacc.y += ((p0.y*q0 + p1.y*q1) + (p2.y*q2 + p3.y*q3)) + ((p4.y*q4 + p5.y*q5) + (p6.y*q6 + p7.y*q7));
            uacc.z += ((p0.z*q0 + p1.z*q1) + (p2.z*q2 + p3.z*q3)) + ((p4.z*q4 + p5.z*q5) + (p6.z*q6 + p7.z*q7));
            uacc.w += ((p0.w*q0 + p1.w*q1) + (p2.w*q2 + p3.w*q3)) + ((p4.w*q4 + p5.w*q5) + (p6.w*q6 + p7.w*q7));
        }
        for (; i < hi; ++i) {
            const int r0 = GET2(i);
            const float4 p0 = *(const float4*)&predb[(size_t)r0*D_ + c];
            const float n0 = wave_sum64(p0.x*p0.x + p0.y*p0.y + p0.z*p0.z + p0.w*p0.w);
            const float q0 = __frsqrt_rn(n0);
            acc.x  += p0.x;    acc.y  += p0.y;    acc.z  += p0.z;    acc.w  += p0.w;
            uacc.x += p0.x*q0; uacc.y += p0.y*q0; uacc.z += p0.z*q0; uacc.w += p0.w*q0;
        }
        #undef GET2
    } else if (cnt > 128) {
        for (; i < hi; ++i) {
            const int r0 = sortb[i];
            const float4 p0 = *(const float4*)&predb[(size_t)r0*D_ + c];
            const float n0 = wave_sum64(p0.x*p0.x + p0.y*p0.y + p0.z*p0.z + p0.w*p0.w);
            const float q0 = __frsqrt_rn(n0);
            acc.x  += p0.x;    acc.y  += p0.y;    acc.z  += p0.z;    acc.w  += p0.w;
            uacc.x += p0.x*q0; uacc.y += p0.y*q0; uacc.z += p0.z*q0; uacc.w += p0.w*q0;
        }
    }

    // ---- combine the two halves (single barrier, tiny epilogue) ----
    *(float4*)&comb[sub][h][0][c] = acc;
    *(float4*)&comb[sub][h][1][c] = uacc;
    __syncthreads();
    if (h != 0) return;

    const float4 a2 = *(const float4*)&comb[sub][1][0][c];
    const float4 u2 = *(const float4*)&comb[sub][1][1][c];
    acc.x  += a2.x;  acc.y  += a2.y;  acc.z  += a2.z;  acc.w  += a2.w;
    uacc.x += u2.x;  uacc.y += u2.y;  uacc.z += u2.z;  uacc.w += u2.w;

    *(float4*)&sums[(size_t)gi*D_ + c] = acc;
    if (cnt == 0) {
        if (lane == 0) pull_g[gi] = 0.f;
        return;
    }
    const float ssq = wave_sum64(acc.x*acc.x + acc.y*acc.y + acc.z*acc.z + acc.w*acc.w);
    const float dus = wave_sum64(uacc.x*acc.x + uacc.y*acc.y + uacc.z*acc.z + uacc.w*acc.w);
    if (lane == 0) pull_g[gi] = (float)cnt - dus / sqrtf(ssq);
}

// ---- K2: per-image push + pull combine; last image-finisher writes out[0] ----
__global__ __launch_bounds__(256) void k_tags(const float* __restrict__ sums,
                                              const int* __restrict__ counts,
                                              const float* __restrict__ pull_g,
                                              float* __restrict__ lossv,
                                              int* __restrict__ done,
                                              float* __restrict__ out) {
    const int b = blockIdx.x;
    const int tid = threadIdx.x;
    const int lane = tid & 63;
    const int wave = tid >> 6;
    __shared__ float s_acc[D_];
    __shared__ float redA[256];
    __shared__ float redB[256];

    for (int i = tid; i < D_; i += 256) s_acc[i] = 0.f;
    __syncthreads();

    const int c = lane * 4;
    float4 sl = make_float4(0.f, 0.f, 0.f, 0.f);
    for (int g = wave; g < G_; g += 4) {
        const int cnt = counts[b*G_ + g];
        const float inv = 1.0f / fmaxf((float)cnt, 1.0f);
        const float4 sm = *(const float4*)&sums[((size_t)(b*G_ + g))*D_ + c];
        const float tx = sm.x*inv, tyv = sm.y*inv, tz = sm.z*inv, tw = sm.w*inv;
        const float sq = wave_sum64(tx*tx + tyv*tyv + tz*tz + tw*tw);
        if (cnt > 0) {
            const float it = __frsqrt_rn(sq);
            sl.x += tx*it; sl.y += tyv*it; sl.z += tz*it; sl.w += tw*it;
        }
    }
    atomicAdd(&s_acc[c+0], sl.x);
    atomicAdd(&s_acc[c+1], sl.y);
    atomicAdd(&s_acc[c+2], sl.z);
    atomicAdd(&s_acc[c+3], sl.w);
    __syncthreads();

    const int cnt_t = counts[b*G_ + tid];
    const float v = s_acc[tid];
    redA[tid] = v * v;
    redB[tid] = (cnt_t > 0) ? 1.f : 0.f;
    __syncthreads();
    for (int s = 128; s > 0; s >>= 1) {
        if (tid < s) { redA[tid] += redA[tid + s]; redB[tid] += redB[tid + s]; }
        __syncthreads();
    }
    float ssq = 0.f, obj = 0.f;
    if (tid == 0) { ssq = redA[0]; obj = redB[0]; }
    __syncthreads();

    redA[tid] = (cnt_t > 0) ? pull_g[b*G_ + tid] / (float)cnt_t : 0.f;
    __syncthreads();
    for (int s = 128; s > 0; s >>= 1) {
        if (tid < s) redA[tid] += redA[tid + s];
        __syncthreads();
    }
    if (tid == 0) {
        const float push = (obj*obj - 2.f*obj + ssq) / (((obj - 1.f)*obj + EPSF) * 2.f);
        const float pull = redA[0] / (obj + EPSF);
        const float loss = (obj > 1.f) ? (push + pull) : 0.f;
        __hip_atomic_store(&lossv[b], loss, __ATOMIC_RELEASE, __HIP_MEMORY_SCOPE_AGENT);
        const int o = __hip_atomic_fetch_add(&done[0], 1, __ATOMIC_ACQ_REL,
                                             __HIP_MEMORY_SCOPE_AGENT);
        if (o == B_ - 1) {    // last image: final mean
            float t = 0.f;
            #pragma unroll
            for (int bb = 0; bb < B_; ++bb)
                t += __hip_atomic_load(&lossv[bb], __ATOMIC_RELAXED, __HIP_MEMORY_SCOPE_AGENT);
            out[0] = t * (1.0f / (float)B_);
        }
    }
}

extern "C" void kernel_launch(void* const* d_in, const int* in_sizes, int n_in,
                              void* d_out, int out_size, void* d_ws, size_t ws_size,
                              hipStream_t stream) {
    const float* pred = (const float*)d_in[0];
    const int*   gt   = (const int*)d_in[1];
    float* out = (float*)d_out;

    char* ws = (char*)d_ws;
    const size_t SZ_SUMS = (size_t)B_*G_*D_*sizeof(float);   // 4 MiB
    const size_t SZ_I    = (size_t)B_*G_*sizeof(int);        // 16 KiB each

    float* sums    = (float*)ws;                               ws += SZ_SUMS;
    int*   counts  = (int*)ws;                                 ws += SZ_I;
    int*   starts  = (int*)ws;                                 ws += SZ_I;
    float* pull_g  = (float*)ws;                               ws += SZ_I;
    float* lossv   = (float*)ws;                               ws += 64*sizeof(float);
    int*   done    = (int*)ws;                                 ws += 64*sizeof(int);
    int*   sorted  = (int*)ws;                                 // B*N ints = 1 MiB

    k_sort  <<<B_,      1024, 0, stream>>>(gt, counts, starts, sorted, done);
    k_fused <<<B_*G_/2,  256, 0, stream>>>(pred, sorted, starts, counts, sums, pull_g);
    k_tags  <<<B_,       256, 0, stream>>>(sums, counts, pull_g, lossv, done, out);
}

// Round 11
// 85.442 us; speedup vs baseline: 2.0506x; 1.0620x over previous
//
#include <hip/hip_runtime.h>

#define B_ 16
#define N_ 16384
#define D_ 256
#define G_ 256
#define EPSF 1e-6f
#define CHUNKS 16
#define CROWS (N_/CHUNKS)   // 1024 rows per chunk

// ---- DPP wave-64 sum: row_shr 1/2/4/8 + row_bcast15/31, broadcast via readlane(63).
template <int CTRL>
__device__ __forceinline__ float dpp_add_step(float x) {
    const int y = __builtin_amdgcn_update_dpp(0, __float_as_int(x), CTRL, 0xF, 0xF, false);
    return x + __int_as_float(y);
}
__device__ __forceinline__ float wave_sum64(float x) {
    x = dpp_add_step<0x111>(x);   // row_shr:1
    x = dpp_add_step<0x112>(x);   // row_shr:2
    x = dpp_add_step<0x114>(x);   // row_shr:4
    x = dpp_add_step<0x118>(x);   // row_shr:8
    x = dpp_add_step<0x142>(x);   // row_bcast15
    x = dpp_add_step<0x143>(x);   // row_bcast31 -> lane 63 has wave total
    return __int_as_float(__builtin_amdgcn_readlane(__float_as_int(x), 63));
}

// ---- K0a: per-chunk histogram (256 blocks = 16 images x 16 chunks) ----
__global__ __launch_bounds__(256) void k_hist(const int* __restrict__ gt,
                                              int* __restrict__ chist,
                                              int* __restrict__ done) {
    __shared__ int h[G_];
    const int tid = threadIdx.x, blk = blockIdx.x;
    if (blk == 0 && tid == 0) done[0] = 0;
    h[tid] = 0;
    __syncthreads();
    const int4 g4 = *(const int4*)&gt[blk*CROWS + tid*4];
    atomicAdd(&h[g4.x], 1);
    atomicAdd(&h[g4.y], 1);
    atomicAdd(&h[g4.z], 1);
    atomicAdd(&h[g4.w], 1);
    __syncthreads();
    chist[blk*G_ + tid] = h[tid];
}

// ---- K0b: per-chunk scan + scatter (256 blocks). Each block re-derives the
//      image-wide group scan from the 16 chunk-hists, seeds its chunk's
//      cursors, scatters its 1024 rows. Chunk-0 writes counts/starts. ----
__global__ __launch_bounds__(256) void k_scatscan(const int* __restrict__ gt,
                                                  const int* __restrict__ chist,
                                                  int* __restrict__ counts,
                                                  int* __restrict__ starts,
                                                  int* __restrict__ sorted) {
    __shared__ int scn[G_];
    __shared__ int cur[G_];
    const int g = threadIdx.x, blk = blockIdx.x;
    const int b = blk >> 4, chunk = blk & 15;

    int tot = 0, pre = 0;
    #pragma unroll
    for (int cc = 0; cc < CHUNKS; ++cc) {
        const int v = chist[((b<<4) + cc)*G_ + g];
        pre += (cc < chunk) ? v : 0;
        tot += v;
    }
    scn[g] = tot;
    __syncthreads();
    for (int off = 1; off < G_; off <<= 1) {
        const int v2 = (g >= off) ? scn[g - off] : 0;
        __syncthreads();
        scn[g] += v2;
        __syncthreads();
    }
    const int st = scn[g] - tot;               // exclusive over groups
    if (chunk == 0) { counts[b*G_ + g] = tot; starts[b*G_ + g] = st; }
    cur[g] = st + pre;
    __syncthreads();

    const int rbase = chunk * CROWS;
    const int4 g4 = *(const int4*)&gt[b*N_ + rbase + g*4];
    const int r = rbase + g*4;
    int* sb = sorted + b*N_;
    sb[atomicAdd(&cur[g4.x], 1)] = r;
    sb[atomicAdd(&cur[g4.y], 1)] = r + 1;
    sb[atomicAdd(&cur[g4.z], 1)] = r + 2;
    sb[atomicAdd(&cur[g4.w], 1)] = r + 3;
}

// ---- K1: TWO waves per (b,g) group (round-10 verbatim) ----
__global__ __launch_bounds__(256, 5) void k_fused(const float* __restrict__ pred,
                                                  const int* __restrict__ sorted,
                                                  const int* __restrict__ starts,
                                                  const int* __restrict__ counts,
                                                  float* __restrict__ sums,
                                                  float* __restrict__ pull_g) {
    __shared__ float comb[2][2][2][D_];   // [sub][half][S|U][dim] = 8 KiB
    const int tid = threadIdx.x, lane = tid & 63, w = tid >> 6;
    const int sub = w >> 1, h = w & 1;
    const int gi = (blockIdx.x << 1) | sub;        // = b*G_ + g
    const int b = gi >> 8;
    const int start = starts[gi], cnt = counts[gi];
    const int c = lane * 4;

    const float* predb = pred + (size_t)b*N_*D_;
    const int*   sortb = sorted + b*N_ + start;

    float4 acc  = make_float4(0.f,0.f,0.f,0.f);    // S partial (this lane's 4 dims)
    float4 uacc = make_float4(0.f,0.f,0.f,0.f);    // U partial

    const int half = (cnt + 1) >> 1;
    const int lo = h * half;
    const int hi = min(cnt, lo + half);
    int i = lo;

    if (cnt > 0 && cnt <= 128) {
        const int ids0 = sortb[min(lane, cnt-1)];
        int ids1 = 0;
        if (cnt > 64) ids1 = sortb[min(64 + lane, cnt-1)];
        #define GET2(k) (((k) < 64) ? __builtin_amdgcn_readlane(ids0, (k)) \
                                    : __builtin_amdgcn_readlane(ids1, (k) - 64))
        for (; i + 8 <= hi; i += 8) {
            const int r0 = GET2(i+0), r1 = GET2(i+1), r2 = GET2(i+2), r3 = GET2(i+3);
            const int r4 = GET2(i+4), r5 = GET2(i+5), r6 = GET2(i+6), r7 = GET2(i+7);
            const float4 p0 = *(const float4*)&predb[(size_t)r0*D_ + c];
            const float4 p1 = *(const float4*)&predb[(size_t)r1*D_ + c];
            const float4 p2 = *(const float4*)&predb[(size_t)r2*D_ + c];
            const float4 p3 = *(const float4*)&predb[(size_t)r3*D_ + c];
            const float4 p4 = *(const float4*)&predb[(size_t)r4*D_ + c];
            const float4 p5 = *(const float4*)&predb[(size_t)r5*D_ + c];
            const float4 p6 = *(const float4*)&predb[(size_t)r6*D_ + c];
            const float4 p7 = *(const float4*)&predb[(size_t)r7*D_ + c];
            float n0 = p0.x*p0.x + p0.y*p0.y + p0.z*p0.z + p0.w*p0.w;
            float n1 = p1.x*p1.x + p1.y*p1.y + p1.z*p1.z + p1.w*p1.w;
            float n2 = p2.x*p2.x + p2.y*p2.y + p2.z*p2.z + p2.w*p2.w;
            float n3 = p3.x*p3.x + p3.y*p3.y + p3.z*p3.z + p3.w*p3.w;
            float n4 = p4.x*p4.x + p4.y*p4.y + p4.z*p4.z + p4.w*p4.w;
            float n5 = p5.x*p5.x + p5.y*p5.y + p5.z*p5.z + p5.w*p5.w;
            float n6 = p6.x*p6.x + p6.y*p6.y + p6.z*p6.z + p6.w*p6.w;
            float n7 = p7.x*p7.x + p7.y*p7.y + p7.z*p7.z + p7.w*p7.w;
            n0 = wave_sum64(n0); n1 = wave_sum64(n1);
            n2 = wave_sum64(n2); n3 = wave_sum64(n3);
            n4 = wave_sum64(n4); n5 = wave_sum64(n5);
            n6 = wave_sum64(n6); n7 = wave_sum64(n7);
            const float q0 = __frsqrt_rn(n0), q1 = __frsqrt_rn(n1);
            const float q2 = __frsqrt_rn(n2), q3 = __frsqrt_rn(n3);
            const float q4 = __frsqrt_rn(n4), q5 = __frsqrt_rn(n5);
            const float q6 = __frsqrt_rn(n6), q7 = __frsqrt_rn(n7);
            acc.x  += ((p0.x + p1.x) + (p2.x + p3.x)) + ((p4.x + p5.x) + (p6.x + p7.x));
            acc.y  += ((p0.y + p1.y) + (p2.y + p3.y)) + ((p4.y + p5.y) + (p6.y + p7.y));
            acc.z  += ((p0.z + p1.z) + (p2.z + p3.z)) + ((p4.z + p5.z) + (p6.z + p7.z));
            acc.w  += ((p0.w + p1.w) + (p2.w + p3.w)) + ((p4.w + p5.w) + (p6.w + p7.w));
            uacc.x += ((p0.x*q0 + p1.x*q1) + (p2.x*q2 + p3.x*q3)) + ((p4.x*q4 + p5.x*q5) + (p6.x*q6 + p7.x*q7));
            uacc.y += ((p0.y*q0 + p1.y*q1) + (p2.y*q2 + p3.y*q3)) + ((p4.y*q4 + p5.y*q5) + (p6.y*q6 + p7.y*q7));
            uacc.z += ((p0.z*q0 + p1.z*q1) + (p2.z*q2 + p3.z*q3)) + ((p4.z*q4 + p5.z*q5) + (p6.z*q6 + p7.z*q7));
            uacc.w += ((p0.w*q0 + p1.w*q1) + (p2.w*q2 + p3.w*q3)) + ((p4.w*q4 + p5.w*q5) + (p6.w*q6 + p7.w*q7));
        }
        for (; i < hi; ++i) {
            const int r0 = GET2(i);
            const float4 p0 = *(const float4*)&predb[(size_t)r0*D_ + c];
            const float n0 = wave_sum64(p0.x*p0.x + p0.y*p0.y + p0.z*p0.z + p0.w*p0.w);
            const float q0 = __frsqrt_rn(n0);
            acc.x  += p0.x;    acc.y  += p0.y;    acc.z  += p0.z;    acc.w  += p0.w;
            uacc.x += p0.x*q0; uacc.y += p0.y*q0; uacc.z += p0.z*q0; uacc.w += p0.w*q0;
        }
        #undef GET2
    } else if (cnt > 128) {
        for (; i < hi; ++i) {
            const int r0 = sortb[i];
            const float4 p0 = *(const float4*)&predb[(size_t)r0*D_ + c];
            const float n0 = wave_sum64(p0.x*p0.x + p0.y*p0.y + p0.z*p0.z + p0.w*p0.w);
            const float q0 = __frsqrt_rn(n0);
            acc.x  += p0.x;    acc.y  += p0.y;    acc.z  += p0.z;    acc.w  += p0.w;
            uacc.x += p0.x*q0; uacc.y += p0.y*q0; uacc.z += p0.z*q0; uacc.w += p0.w*q0;
        }
    }

    // ---- combine the two halves (single barrier, tiny epilogue) ----
    *(float4*)&comb[sub][h][0][c] = acc;
    *(float4*)&comb[sub][h][1][c] = uacc;
    __syncthreads();
    if (h != 0) return;

    const float4 a2 = *(const float4*)&comb[sub][1][0][c];
    const float4 u2 = *(const float4*)&comb[sub][1][1][c];
    acc.x  += a2.x;  acc.y  += a2.y;  acc.z  += a2.z;  acc.w  += a2.w;
    uacc.x += u2.x;  uacc.y += u2.y;  uacc.z += u2.z;  uacc.w += u2.w;

    *(float4*)&sums[(size_t)gi*D_ + c] = acc;
    if (cnt == 0) {
        if (lane == 0) pull_g[gi] = 0.f;
        return;
    }
    const float ssq = wave_sum64(acc.x*acc.x + acc.y*acc.y + acc.z*acc.z + acc.w*acc.w);
    const float dus = wave_sum64(uacc.x*acc.x + uacc.y*acc.y + uacc.z*acc.z + uacc.w*acc.w);
    if (lane == 0) pull_g[gi] = (float)cnt - dus / sqrtf(ssq);
}

// ---- K2: per-image push + pull combine; last image-finisher writes out[0] ----
__global__ __launch_bounds__(256) void k_tags(const float* __restrict__ sums,
                                              const int* __restrict__ counts,
                                              const float* __restrict__ pull_g,
                                              float* __restrict__ lossv,
                                              int* __restrict__ done,
                                              float* __restrict__ out) {
    const int b = blockIdx.x;
    const int tid = threadIdx.x;
    const int lane = tid & 63;
    const int wave = tid >> 6;
    __shared__ float s_acc[D_];
    __shared__ float redA[256];
    __shared__ float redB[256];

    for (int i = tid; i < D_; i += 256) s_acc[i] = 0.f;
    __syncthreads();

    const int c = lane * 4;
    float4 sl = make_float4(0.f, 0.f, 0.f, 0.f);
    for (int g = wave; g < G_; g += 4) {
        const int cnt = counts[b*G_ + g];
        const float inv = 1.0f / fmaxf((float)cnt, 1.0f);
        const float4 sm = *(const float4*)&sums[((size_t)(b*G_ + g))*D_ + c];
        const float tx = sm.x*inv, tyv = sm.y*inv, tz = sm.z*inv, tw = sm.w*inv;
        const float sq = wave_sum64(tx*tx + tyv*tyv + tz*tz + tw*tw);
        if (cnt > 0) {
            const float it = __frsqrt_rn(sq);
            sl.x += tx*it; sl.y += tyv*it; sl.z += tz*it; sl.w += tw*it;
        }
    }
    atomicAdd(&s_acc[c+0], sl.x);
    atomicAdd(&s_acc[c+1], sl.y);
    atomicAdd(&s_acc[c+2], sl.z);
    atomicAdd(&s_acc[c+3], sl.w);
    __syncthreads();

    const int cnt_t = counts[b*G_ + tid];
    const float v = s_acc[tid];
    redA[tid] = v * v;
    redB[tid] = (cnt_t > 0) ? 1.f : 0.f;
    __syncthreads();
    for (int s = 128; s > 0; s >>= 1) {
        if (tid < s) { redA[tid] += redA[tid + s]; redB[tid] += redB[tid + s]; }
        __syncthreads();
    }
    float ssq = 0.f, obj = 0.f;
    if (tid == 0) { ssq = redA[0]; obj = redB[0]; }
    __syncthreads();

    redA[tid] = (cnt_t > 0) ? pull_g[b*G_ + tid] / (float)cnt_t : 0.f;
    __syncthreads();
    for (int s = 128; s > 0; s >>= 1) {
        if (tid < s) redA[tid] += redA[tid + s];
        __syncthreads();
    }
    if (tid == 0) {
        const float push = (obj*obj - 2.f*obj + ssq) / (((obj - 1.f)*obj + EPSF) * 2.f);
        const float pull = redA[0] / (obj + EPSF);
        const float loss = (obj > 1.f) ? (push + pull) : 0.f;
        __hip_atomic_store(&lossv[b], loss, __ATOMIC_RELEASE, __HIP_MEMORY_SCOPE_AGENT);
        const int o = __hip_atomic_fetch_add(&done[0], 1, __ATOMIC_ACQ_REL,
                                             __HIP_MEMORY_SCOPE_AGENT);
        if (o == B_ - 1) {    // last image: final mean
            float t = 0.f;
            #pragma unroll
            for (int bb = 0; bb < B_; ++bb)
                t += __hip_atomic_load(&lossv[bb], __ATOMIC_RELAXED, __HIP_MEMORY_SCOPE_AGENT);
            out[0] = t * (1.0f / (float)B_);
        }
    }
}

extern "C" void kernel_launch(void* const* d_in, const int* in_sizes, int n_in,
                              void* d_out, int out_size, void* d_ws, size_t ws_size,
                              hipStream_t stream) {
    const float* pred = (const float*)d_in[0];
    const int*   gt   = (const int*)d_in[1];
    float* out = (float*)d_out;

    char* ws = (char*)d_ws;
    const size_t SZ_SUMS = (size_t)B_*G_*D_*sizeof(float);   // 4 MiB
    const size_t SZ_I    = (size_t)B_*G_*sizeof(int);        // 16 KiB each

    float* sums    = (float*)ws;                               ws += SZ_SUMS;
    int*   counts  = (int*)ws;                                 ws += SZ_I;
    int*   starts  = (int*)ws;                                 ws += SZ_I;
    float* pull_g  = (float*)ws;                               ws += SZ_I;
    float* lossv   = (float*)ws;                               ws += 64*sizeof(float);
    int*   done    = (int*)ws;                                 ws += 64*sizeof(int);
    int*   sorted  = (int*)ws;                                 ws += (size_t)B_*N_*sizeof(int);  // 1 MiB
    int*   chist   = (int*)ws;                                 // B*CHUNKS*G ints = 256 KiB

    k_hist     <<<B_*CHUNKS, 256, 0, stream>>>(gt, chist, done);
    k_scatscan <<<B_*CHUNKS, 256, 0, stream>>>(gt, chist, counts, starts, sorted);
    k_fused    <<<B_*G_/2,   256, 0, stream>>>(pred, sorted, starts, counts, sums, pull_g);
    k_tags     <<<B_,        256, 0, stream>>>(sums, counts, pull_g, lossv, done, out);
}